// Round 11
// baseline (522.201 us; speedup 1.0000x reference)
//
#include <hip/hip_runtime.h>
#include <hip/hip_bf16.h>
#include <math.h>

#define EMBED 128
#define VOCAB 32000
#define MEMN  50
#define BATCH 16
#define NQ    10
#define SQ    20
#define SS    40
#define BN    (BATCH*NQ)   // 160
#define NHOPS 3
#define NV    64           // vocab rows per k_out block

// Measurement round #2: idempotent amplification (R7 technique)
#define EREP 16
#define HREP 32

typedef short v8s __attribute__((ext_vector_type(8)));
typedef float v4f __attribute__((ext_vector_type(4)));

#define MFMA16 __builtin_amdgcn_mfma_f32_16x16x32_bf16

__device__ __forceinline__ float posw(int j, int J, int k) {
    float jf = (float)(j + 1) / (float)J;
    return 1.0f - jf - ((float)(k + 1) / (float)EMBED) * (1.0f - 2.0f * jf);
}

__device__ __forceinline__ short f2bf(float f) {
    __hip_bfloat16 h = __float2bfloat16(f);
    return *(short*)&h;
}
__device__ __forceinline__ float bf2f(short s) {
    __hip_bfloat16 h = *(__hip_bfloat16*)&s;
    return __bfloat162float(h);
}

// ---- Kernel 1 (R10-exact body, x EREP) ----
__global__ void k_embed(const int* __restrict__ cq, const int* __restrict__ story,
                        const float* __restrict__ Bw, const float* __restrict__ Aw,
                        const float* __restrict__ Cw, const float* __restrict__ TA,
                        const float* __restrict__ TC, const float* __restrict__ Hw,
                        float* __restrict__ state, float* __restrict__ memb,
                        float* __restrict__ outb, short* __restrict__ HwBhi,
                        short* __restrict__ HwBlo) {
    int blk = blockIdx.x;
    int t = threadIdx.x;   // 128
    for (int rep = 0; rep < EREP; ++rep) {
        asm volatile("" ::: "memory");
        if (blk < BN) {
            float acc = 0.f;
            #pragma unroll
            for (int s = 0; s < SQ; ++s) {
                int tok = cq[blk * SQ + s];
                acc += Bw[tok * EMBED + t] * posw(s, SQ, t);
            }
            state[blk * EMBED + t] = acc;
        } else if (blk < BN + BATCH * MEMN) {
            int br = blk - BN;
            int r = br % MEMN;
            float ma = TA[r * EMBED + t];
            float mc = TC[r * EMBED + t];
            const int* toks = story + br * SS;
            #pragma unroll 4
            for (int s = 0; s < SS; ++s) {
                int tok = toks[s];
                float w = posw(s, SS, t);
                ma += Aw[tok * EMBED + t] * w;
                mc += Cw[tok * EMBED + t] * w;
            }
            memb[br * EMBED + t] = ma;
            outb[br * EMBED + t] = mc;
        } else {
            int row = blk - (BN + BATCH * MEMN);   // 0..127
            float v = Hw[row * EMBED + t];
            short h = f2bf(v);
            HwBhi[row * EMBED + t] = h;
            HwBlo[row * EMBED + t] = f2bf(v - bf2f(h));
        }
    }
}

// ---- Kernel 2 (R10-exact v4 body, x HREP) ----
__global__ __launch_bounds__(256) void k_hops(const float* __restrict__ memb,
                                              const float* __restrict__ outb,
                                              const short* __restrict__ HwBhi,
                                              const short* __restrict__ HwBlo,
                                              const float* __restrict__ Hb,
                                              const float* __restrict__ state,
                                              __hip_bfloat16* __restrict__ stateb) {
    __shared__ short mem_hi[64][128], mem_lo[64][128];
    __shared__ short outT_hi[128][64], outT_lo[128][64];
    __shared__ short P_hi[16][64], P_lo[16][64];
    __shared__ short resp_hi[16][128], resp_lo[16][128];
    __shared__ float stateM[16][132];
    __shared__ float Lg[16][64];
    __shared__ float Hb_l[128];

    int b = blockIdx.x;
    int t = threadIdx.x;    // 256
    int w = t >> 6;
    int l = t & 63;
    int c16 = l & 15;
    int kg = l >> 4;

    for (int rep = 0; rep < HREP; ++rep) {
        asm volatile("" ::: "memory");
        {
            v8s z = {0,0,0,0,0,0,0,0};
            for (int i = t; i < 64*128/8; i += 256) { ((v8s*)mem_hi)[i] = z; ((v8s*)mem_lo)[i] = z; }
            for (int i = t; i < 128*64/8; i += 256) { ((v8s*)outT_hi)[i] = z; ((v8s*)outT_lo)[i] = z; }
            for (int i = t; i < 16*64/8;  i += 256) { ((v8s*)P_hi)[i] = z; ((v8s*)P_lo)[i] = z; }
            for (int i = t; i < 16*132;   i += 256) ((float*)stateM)[i] = 0.f;
        }
        __syncthreads();

        {
            const float4* mb4 = (const float4*)(memb + (size_t)b * MEMN * EMBED);
            const float4* ob4 = (const float4*)(outb + (size_t)b * MEMN * EMBED);
            for (int i = t; i < MEMN * EMBED / 4; i += 256) {
                int r = i >> 5, c4 = (i & 31) << 2;
                float4 v = mb4[i];
                float4 u = ob4[i];
                float mv[4] = {v.x, v.y, v.z, v.w};
                float ov[4] = {u.x, u.y, u.z, u.w};
                #pragma unroll
                for (int j = 0; j < 4; ++j) {
                    int k = c4 + j;
                    short h = f2bf(mv[j]);
                    int pos = (((k >> 3) ^ (r & 15)) << 3) | (k & 7);
                    mem_hi[r][pos] = h;
                    mem_lo[r][pos] = f2bf(mv[j] - bf2f(h));
                    short g = f2bf(ov[j]);
                    int posT = (((r >> 3) ^ (k & 7)) << 3) | (r & 7);
                    outT_hi[k][posT] = g;
                    outT_lo[k][posT] = f2bf(ov[j] - bf2f(g));
                }
            }
            for (int i = t; i < NQ * EMBED; i += 256) {
                int q = i >> 7, d = i & 127;
                stateM[q][d] = state[((size_t)b * NQ + q) * EMBED + d];
            }
            if (t < 128) Hb_l[t] = Hb[t];
        }
        __syncthreads();

        for (int hop = 0; hop < NHOPS; ++hop) {
            {
                v4f acc = {0.f, 0.f, 0.f, 0.f};
                int mrow = (w << 4) + c16;
                #pragma unroll
                for (int ks = 0; ks < 4; ++ks) {
                    float4 s0 = *(const float4*)&stateM[c16][ks*32 + kg*8];
                    float4 s1 = *(const float4*)&stateM[c16][ks*32 + kg*8 + 4];
                    float sv[8] = {s0.x, s0.y, s0.z, s0.w, s1.x, s1.y, s1.z, s1.w};
                    v8s ah, al;
                    #pragma unroll
                    for (int j = 0; j < 8; ++j) {
                        short h = f2bf(sv[j]);
                        ah[j] = h;
                        al[j] = f2bf(sv[j] - bf2f(h));
                    }
                    int pos = ((ks*4 + kg) ^ (mrow & 15)) << 3;
                    v8s bh = *(const v8s*)&mem_hi[mrow][pos];
                    v8s bl = *(const v8s*)&mem_lo[mrow][pos];
                    acc = MFMA16(ah, bh, acc, 0, 0, 0);
                    acc = MFMA16(al, bh, acc, 0, 0, 0);
                    acc = MFMA16(ah, bl, acc, 0, 0, 0);
                }
                #pragma unroll
                for (int i = 0; i < 4; ++i) Lg[kg*4 + i][(w << 4) + c16] = acc[i];
            }
            __syncthreads();
            for (int q = w; q < NQ; q += 4) {
                float v = (l < MEMN) ? Lg[q][l] : -1e30f;
                float mx = v;
                #pragma unroll
                for (int off = 32; off; off >>= 1) mx = fmaxf(mx, __shfl_xor(mx, off, 64));
                float e = (l < MEMN) ? __expf(v - mx) : 0.f;
                float ss = e;
                #pragma unroll
                for (int off = 32; off; off >>= 1) ss += __shfl_xor(ss, off, 64);
                if (l < MEMN) {
                    float p = e / ss;
                    short h = f2bf(p);
                    int pos = (((l >> 3) ^ (q & 7)) << 3) | (l & 7);
                    P_hi[q][pos] = h;
                    P_lo[q][pos] = f2bf(p - bf2f(h));
                }
            }
            __syncthreads();
            {
                v8s ph[2], pl[2];
                #pragma unroll
                for (int ks = 0; ks < 2; ++ks) {
                    int pos = ((ks*4 + kg) ^ (c16 & 7)) << 3;
                    ph[ks] = *(const v8s*)&P_hi[c16][pos];
                    pl[ks] = *(const v8s*)&P_lo[c16][pos];
                }
                #pragma unroll
                for (int tile = 0; tile < 2; ++tile) {
                    int d = (w << 4) + tile * 64;
                    int orow = d + c16;
                    v4f acc = {0.f, 0.f, 0.f, 0.f};
                    #pragma unroll
                    for (int ks = 0; ks < 2; ++ks) {
                        int pos = ((ks*4 + kg) ^ (orow & 7)) << 3;
                        v8s bh = *(const v8s*)&outT_hi[orow][pos];
                        v8s bl = *(const v8s*)&outT_lo[orow][pos];
                        acc = MFMA16(ph[ks], bh, acc, 0, 0, 0);
                        acc = MFMA16(pl[ks], bh, acc, 0, 0, 0);
                        acc = MFMA16(ph[ks], bl, acc, 0, 0, 0);
                    }
                    #pragma unroll
                    for (int i = 0; i < 4; ++i) {
                        int row = kg*4 + i, col = d + c16;
                        float v = acc[i];
                        short h = f2bf(v);
                        int pos = (((col >> 3) ^ (row & 15)) << 3) | (col & 7);
                        resp_hi[row][pos] = h;
                        resp_lo[row][pos] = f2bf(v - bf2f(h));
                    }
                }
            }
            __syncthreads();
            {
                v8s rh[4], rl[4];
                #pragma unroll
                for (int ks = 0; ks < 4; ++ks) {
                    int pos = ((ks*4 + kg) ^ (c16 & 15)) << 3;
                    rh[ks] = *(const v8s*)&resp_hi[c16][pos];
                    rl[ks] = *(const v8s*)&resp_lo[c16][pos];
                }
                #pragma unroll
                for (int tile = 0; tile < 2; ++tile) {
                    int d = (w << 4) + tile * 64;
                    int hrow = d + c16;
                    const v8s* gh = (const v8s*)(HwBhi + (size_t)hrow * EMBED);
                    const v8s* gl = (const v8s*)(HwBlo + (size_t)hrow * EMBED);
                    v4f acc = {0.f, 0.f, 0.f, 0.f};
                    #pragma unroll
                    for (int ks = 0; ks < 4; ++ks) {
                        v8s bh = gh[ks*4 + kg];
                        v8s bl = gl[ks*4 + kg];
                        acc = MFMA16(rh[ks], bh, acc, 0, 0, 0);
                        acc = MFMA16(rl[ks], bh, acc, 0, 0, 0);
                        acc = MFMA16(rh[ks], bl, acc, 0, 0, 0);
                    }
                    #pragma unroll
                    for (int i = 0; i < 4; ++i) {
                        int row = kg*4 + i, col = d + c16;
                        stateM[row][col] = acc[i] + Hb_l[col] + stateM[row][col];
                    }
                }
            }
            __syncthreads();
        }
        for (int i = t; i < NQ * EMBED; i += 256) {
            int q = i >> 7, d = i & 127;
            stateb[((size_t)b * NQ + q) * EMBED + d] = __float2bfloat16(stateM[q][d]);
        }
        __syncthreads();   // protect stateM/LDS before next rep's zero-fill
    }
}

// ---- Kernel 3 (R10-exact): MFMA GEMM out[160,32000] ----
__global__ __launch_bounds__(256) void k_out(const __hip_bfloat16* __restrict__ stateb,
                                             const float* __restrict__ outw,
                                             float* __restrict__ out) {
    __shared__ __align__(16) __hip_bfloat16 Alds[BN][EMBED + 8];
    __shared__ __align__(16) __hip_bfloat16 Blds[NV][EMBED + 8];
    int t = threadIdx.x;
    int vbase = blockIdx.x * NV;

    #pragma unroll
    for (int i = 0; i < 10; ++i) {
        int e = t + i * 256;
        int row = e >> 4, c8 = (e & 15) << 3;
        *(int4*)&Alds[row][c8] = *(const int4*)&stateb[row * EMBED + c8];
    }
    #pragma unroll
    for (int i = 0; i < 8; ++i) {
        int e = t + i * 256;
        int row = e >> 5, c4 = (e & 31) << 2;
        float4 w = *(const float4*)&outw[(size_t)(vbase + row) * EMBED + c4];
        short4 p;
        p.x = f2bf(w.x); p.y = f2bf(w.y); p.z = f2bf(w.z); p.w = f2bf(w.w);
        *(short4*)&Blds[row][c4] = p;
    }
    __syncthreads();

    int wv = t >> 6;
    int l = t & 63;
    int col16 = l & 15;
    int kg = l >> 4;

    v8s bfrag[4];
    #pragma unroll
    for (int k4 = 0; k4 < 4; ++k4)
        bfrag[k4] = *(v8s*)&Blds[(wv << 4) + col16][k4 * 32 + kg * 8];

    v4f acc[10];
    #pragma unroll
    for (int m = 0; m < 10; ++m) acc[m] = (v4f){0.f, 0.f, 0.f, 0.f};

    #pragma unroll
    for (int k4 = 0; k4 < 4; ++k4) {
        #pragma unroll
        for (int m = 0; m < 10; ++m) {
            v8s af = *(v8s*)&Alds[m * 16 + col16][k4 * 32 + kg * 8];
            acc[m] = MFMA16(af, bfrag[k4], acc[m], 0, 0, 0);
        }
    }

    int colg = vbase + (wv << 4) + col16;
    #pragma unroll
    for (int m = 0; m < 10; ++m) {
        #pragma unroll
        for (int i = 0; i < 4; ++i) {
            out[(size_t)(m * 16 + kg * 4 + i) * VOCAB + colg] = acc[m][i];
        }
    }
}

extern "C" void kernel_launch(void* const* d_in, const int* in_sizes, int n_in,
                              void* d_out, int out_size, void* d_ws, size_t ws_size,
                              hipStream_t stream) {
    const int*   ctx_query = (const int*)  d_in[0];
    const int*   story     = (const int*)  d_in[1];
    const float* A_w       = (const float*)d_in[2];
    const float* C_w       = (const float*)d_in[3];
    const float* B_w       = (const float*)d_in[4];
    const float* H_w       = (const float*)d_in[5];
    const float* H_b       = (const float*)d_in[6];
    const float* out_w     = (const float*)d_in[7];
    const float* TA        = (const float*)d_in[8];
    const float* TC        = (const float*)d_in[9];
    float* out = (float*)d_out;

    float* ws    = (float*)d_ws;
    float* state = ws;                                   // 160*128 f32
    float* memb  = state + BN * EMBED;                   // 800*128 f32
    float* outb  = memb + BATCH * MEMN * EMBED;          // 800*128 f32
    short* HwBhi = (short*)(outb + BATCH * MEMN * EMBED);// 128*128 bf16
    short* HwBlo = HwBhi + EMBED * EMBED;                // 128*128 bf16
    __hip_bfloat16* stateb = (__hip_bfloat16*)(HwBlo + EMBED * EMBED);  // 160*128 bf16

    k_embed<<<BN + BATCH * MEMN + EMBED, 128, 0, stream>>>(
        ctx_query, story, B_w, A_w, C_w, TA, TC, H_w, state, memb, outb, HwBhi, HwBlo);
    k_hops<<<BATCH, 256, 0, stream>>>(memb, outb, HwBhi, HwBlo, H_b, state, stateb);
    k_out<<<VOCAB / NV, 256, 0, stream>>>(stateb, out_w, out);
}

// Round 12
// 42.280 us; speedup vs baseline: 12.3510x; 12.3510x over previous
//
#include <hip/hip_runtime.h>
#include <hip/hip_bf16.h>
#include <math.h>

#define EMBED 128
#define VOCAB 32000
#define MEMN  50
#define BATCH 16
#define NQ    10
#define SQ    20
#define SS    40
#define BN    (BATCH*NQ)   // 160
#define NHOPS 3
#define NV    64           // vocab rows per k_out block

typedef short v8s __attribute__((ext_vector_type(8)));
typedef float v4f __attribute__((ext_vector_type(4)));

#define MFMA16 __builtin_amdgcn_mfma_f32_16x16x32_bf16

__device__ __forceinline__ float posw(int j, int J, int k) {
    float jf = (float)(j + 1) / (float)J;
    return 1.0f - jf - ((float)(k + 1) / (float)EMBED) * (1.0f - 2.0f * jf);
}

__device__ __forceinline__ short f2bf(float f) {
    __hip_bfloat16 h = __float2bfloat16(f);
    return *(short*)&h;
}
__device__ __forceinline__ float bf2f(short s) {
    __hip_bfloat16 h = *(__hip_bfloat16*)&s;
    return __bfloat162float(h);
}

__device__ __forceinline__ float wave_softmax(float v, int l) {
    float mx = v;
    #pragma unroll
    for (int off = 32; off; off >>= 1) mx = fmaxf(mx, __shfl_xor(mx, off, 64));
    float e = (l < MEMN) ? __expf(v - mx) : 0.f;
    float ss = e;
    #pragma unroll
    for (int off = 32; off; off >>= 1) ss += __shfl_xor(ss, off, 64);
    return e / ss;
}

// ---- Kernel 1 (R10-exact): query | story | Hw hi/lo split ----
__global__ void k_embed(const int* __restrict__ cq, const int* __restrict__ story,
                        const float* __restrict__ Bw, const float* __restrict__ Aw,
                        const float* __restrict__ Cw, const float* __restrict__ TA,
                        const float* __restrict__ TC, const float* __restrict__ Hw,
                        float* __restrict__ state, float* __restrict__ memb,
                        float* __restrict__ outb, short* __restrict__ HwBhi,
                        short* __restrict__ HwBlo) {
    int blk = blockIdx.x;
    int t = threadIdx.x;   // 128
    if (blk < BN) {
        float acc = 0.f;
        #pragma unroll
        for (int s = 0; s < SQ; ++s) {
            int tok = cq[blk * SQ + s];
            acc += Bw[tok * EMBED + t] * posw(s, SQ, t);
        }
        state[blk * EMBED + t] = acc;
    } else if (blk < BN + BATCH * MEMN) {
        int br = blk - BN;
        int r = br % MEMN;
        float ma = TA[r * EMBED + t];
        float mc = TC[r * EMBED + t];
        const int* toks = story + br * SS;
        #pragma unroll 4
        for (int s = 0; s < SS; ++s) {
            int tok = toks[s];
            float w = posw(s, SS, t);
            ma += Aw[tok * EMBED + t] * w;
            mc += Cw[tok * EMBED + t] * w;
        }
        memb[br * EMBED + t] = ma;
        outb[br * EMBED + t] = mc;
    } else {
        int row = blk - (BN + BATCH * MEMN);   // 0..127
        float v = Hw[row * EMBED + t];
        short h = f2bf(v);
        HwBhi[row * EMBED + t] = h;
        HwBlo[row * EMBED + t] = f2bf(v - bf2f(h));
    }
}

// ---- Kernel 2 v5: algebraic hops. Per-batch:
//   OHm = outm @ Hw^T            [50x128]  (MFMA split-bf16)
//   G   = memb @ OHm^T(k=d)      [50x50]   (MFMA split-bf16)
//   l1  = state . memb ; memHb via Hb as state-row 10 (free)
//   recursion in 50-dim logit space (wave-local, zero barriers)
//   state_f = state1 + 3*Hb + Psum . OHm  (exact by linearity of H)
__global__ __launch_bounds__(256) void k_hops(const float* __restrict__ memb,
                                              const float* __restrict__ outb,
                                              const short* __restrict__ HwBhi,
                                              const short* __restrict__ HwBlo,
                                              const float* __restrict__ Hb,
                                              const float* __restrict__ state,
                                              __hip_bfloat16* __restrict__ stateb) {
    __shared__ short mem_hi[64][128], mem_lo[64][128];   // 32 KB
    __shared__ short out_hi[64][128], out_lo[64][128];   // 32 KB
    __shared__ short OH_hi[64][128], OH_lo[64][128];     // 32 KB
    __shared__ float G[64][65];                          // 16.6 KB
    __shared__ float stateM[16][132];                    // 8.4 KB (row 10 = Hb)
    __shared__ float Lg[16][65];                         // 4.2 KB (row 10 = memHb)
    __shared__ float Ps[16][53];                         // 3.4 KB

    int b = blockIdx.x;
    int t = threadIdx.x;    // 256
    int w = t >> 6;
    int l = t & 63;
    int c16 = l & 15;
    int kg = l >> 4;

    // ---- Phase 1: stage (v8s chunk-XOR swizzled writes: conflict-free) ----
    {
        const float* mb = memb + (size_t)b * MEMN * EMBED;
        const float* ob = outb + (size_t)b * MEMN * EMBED;
        for (int i = t; i < MEMN * 16; i += 256) {       // (row, 8-dim chunk)
            int r = i >> 4, c8 = i & 15;
            const float4* m4 = (const float4*)&mb[r * EMBED + (c8 << 3)];
            const float4* o4 = (const float4*)&ob[r * EMBED + (c8 << 3)];
            float4 v0 = m4[0], v1 = m4[1], u0 = o4[0], u1 = o4[1];
            float mv[8] = {v0.x,v0.y,v0.z,v0.w,v1.x,v1.y,v1.z,v1.w};
            float ov[8] = {u0.x,u0.y,u0.z,u0.w,u1.x,u1.y,u1.z,u1.w};
            v8s mh, ml, oh, ol;
            #pragma unroll
            for (int j = 0; j < 8; ++j) {
                short h = f2bf(mv[j]); mh[j] = h; ml[j] = f2bf(mv[j] - bf2f(h));
                short g = f2bf(ov[j]); oh[j] = g; ol[j] = f2bf(ov[j] - bf2f(g));
            }
            int pos = (c8 ^ (r & 15)) << 3;
            *(v8s*)&mem_hi[r][pos] = mh;
            *(v8s*)&mem_lo[r][pos] = ml;
            *(v8s*)&out_hi[r][pos] = oh;
            *(v8s*)&out_lo[r][pos] = ol;
        }
        for (int i = t; i < 14 * 16; i += 256) {         // zero rows 50..63
            int r = 50 + (i >> 4), c8 = i & 15;
            v8s z = {0,0,0,0,0,0,0,0};
            int pos = (c8 ^ (r & 15)) << 3;
            *(v8s*)&mem_hi[r][pos] = z;
            *(v8s*)&mem_lo[r][pos] = z;
            *(v8s*)&out_hi[r][pos] = z;
            *(v8s*)&out_lo[r][pos] = z;
        }
        for (int i = t; i < 16 * 132; i += 256) {        // stateM: q<10 state, q==10 Hb, else 0
            int q = i / 132, d = i - q * 132;
            float v = 0.f;
            if (d < EMBED) {
                if (q < NQ) v = state[((size_t)b * NQ + q) * EMBED + d];
                else if (q == NQ) v = Hb[d];
            }
            (&stateM[0][0])[i] = v;
        }
    }
    __syncthreads();

    // ---- Phase 2: OHm[s][d] = sum_k outm[s,k]*Hw[d,k]  (+ l1 tile) ----
    {
        int stile = w;
        v8s ah[4], al[4];
        #pragma unroll
        for (int ks = 0; ks < 4; ++ks) {
            int arow = (stile << 4) + c16;
            int pos = (((ks * 4 + kg) ^ (arow & 15)) << 3);
            ah[ks] = *(const v8s*)&out_hi[arow][pos];
            al[ks] = *(const v8s*)&out_lo[arow][pos];
        }
        #pragma unroll
        for (int dt = 0; dt < 8; ++dt) {
            int brow = (dt << 4) + c16;
            const v8s* gh = (const v8s*)(HwBhi + (size_t)brow * EMBED);
            const v8s* gl = (const v8s*)(HwBlo + (size_t)brow * EMBED);
            v4f A1 = {0,0,0,0}, A2 = {0,0,0,0}, A3 = {0,0,0,0};
            #pragma unroll
            for (int ks = 0; ks < 4; ++ks) {
                v8s bh = gh[ks * 4 + kg], bl = gl[ks * 4 + kg];
                A1 = MFMA16(ah[ks], bh, A1, 0, 0, 0);
                A2 = MFMA16(al[ks], bh, A2, 0, 0, 0);
                A3 = MFMA16(ah[ks], bl, A3, 0, 0, 0);
            }
            #pragma unroll
            for (int e = 0; e < 4; ++e) {
                int s = (stile << 4) + kg * 4 + e;
                int d = (dt << 4) + c16;
                float v = A1[e] + A2[e] + A3[e];
                short h = f2bf(v);
                int pp = (((d >> 3) ^ (s & 15)) << 3) | (d & 7);
                OH_hi[s][pp] = h;
                OH_lo[s][pp] = f2bf(v - bf2f(h));
            }
        }
        // l1: C[q][r-cols w*16..+15]; A = stateM rows (row 10 = Hb -> memHb)
        {
            int brow = (w << 4) + c16;
            v4f A1 = {0,0,0,0}, A2 = {0,0,0,0}, A3 = {0,0,0,0};
            #pragma unroll
            for (int ks = 0; ks < 4; ++ks) {
                float4 s0 = *(const float4*)&stateM[c16][ks * 32 + kg * 8];
                float4 s1 = *(const float4*)&stateM[c16][ks * 32 + kg * 8 + 4];
                float sv[8] = {s0.x,s0.y,s0.z,s0.w,s1.x,s1.y,s1.z,s1.w};
                v8s sh, sl;
                #pragma unroll
                for (int j = 0; j < 8; ++j) {
                    short h = f2bf(sv[j]); sh[j] = h; sl[j] = f2bf(sv[j] - bf2f(h));
                }
                int pos = (((ks * 4 + kg) ^ (brow & 15)) << 3);
                v8s bh = *(const v8s*)&mem_hi[brow][pos];
                v8s bl = *(const v8s*)&mem_lo[brow][pos];
                A1 = MFMA16(sh, bh, A1, 0, 0, 0);
                A2 = MFMA16(sl, bh, A2, 0, 0, 0);
                A3 = MFMA16(sh, bl, A3, 0, 0, 0);
            }
            #pragma unroll
            for (int e = 0; e < 4; ++e)
                Lg[kg * 4 + e][(w << 4) + c16] = A1[e] + A2[e] + A3[e];
        }
    }
    __syncthreads();

    // ---- Phase 3: G[r][s] = sum_d memb[r,d]*OHm[s,d] ----
    {
        int rtile = w;
        v8s ah[4], al[4];
        #pragma unroll
        for (int ks = 0; ks < 4; ++ks) {
            int arow = (rtile << 4) + c16;
            int pos = (((ks * 4 + kg) ^ (arow & 15)) << 3);
            ah[ks] = *(const v8s*)&mem_hi[arow][pos];
            al[ks] = *(const v8s*)&mem_lo[arow][pos];
        }
        #pragma unroll
        for (int st = 0; st < 4; ++st) {
            int brow = (st << 4) + c16;
            v4f A1 = {0,0,0,0}, A2 = {0,0,0,0}, A3 = {0,0,0,0};
            #pragma unroll
            for (int ks = 0; ks < 4; ++ks) {
                int pos = (((ks * 4 + kg) ^ (brow & 15)) << 3);
                v8s bh = *(const v8s*)&OH_hi[brow][pos];
                v8s bl = *(const v8s*)&OH_lo[brow][pos];
                A1 = MFMA16(ah[ks], bh, A1, 0, 0, 0);
                A2 = MFMA16(al[ks], bh, A2, 0, 0, 0);
                A3 = MFMA16(ah[ks], bl, A3, 0, 0, 0);
            }
            #pragma unroll
            for (int e = 0; e < 4; ++e)
                G[(rtile << 4) + kg * 4 + e][(st << 4) + c16] = A1[e] + A2[e] + A3[e];
        }
    }
    __syncthreads();

    // ---- Phase 4: 50-dim recursion, wave-local (queries w, w+4, w+8) ----
    {
        float lg0 = (l < MEMN) ? Lg[w][l] : -1e30f;
        float lg1 = (l < MEMN) ? Lg[w + 4][l] : -1e30f;
        float lg2 = (l < MEMN && w < 2) ? Lg[w + 8][l] : -1e30f;
        float mhb = (l < MEMN) ? Lg[NQ][l] : 0.f;
        float ps0 = 0.f, ps1 = 0.f, ps2 = 0.f;
        #pragma unroll
        for (int hop = 0; hop < NHOPS; ++hop) {
            float p0 = wave_softmax(lg0, l);
            float p1 = wave_softmax(lg1, l);
            float p2 = wave_softmax(lg2, l);
            ps0 += p0; ps1 += p1; ps2 += p2;
            if (hop == NHOPS - 1) break;
            if (l < MEMN) {
                Ps[w][l] = p0;
                Ps[w + 4][l] = p1;
                if (w < 2) Ps[w + 8][l] = p2;
            }
            asm volatile("" ::: "memory");
            float a0 = 0.f, a1 = 0.f, a2 = 0.f;
            float b0 = 0.f, b1 = 0.f, b2 = 0.f;
            for (int s = 0; s < MEMN; s += 2) {
                float g0 = G[l][s], g1 = G[l][s + 1];
                a0 += g0 * Ps[w][s];      b0 += g1 * Ps[w][s + 1];
                a1 += g0 * Ps[w + 4][s];  b1 += g1 * Ps[w + 4][s + 1];
                if (w < 2) { a2 += g0 * Ps[w + 8][s]; b2 += g1 * Ps[w + 8][s + 1]; }
            }
            lg0 += mhb + (a0 + b0);
            lg1 += mhb + (a1 + b1);
            lg2 += mhb + (a2 + b2);
        }
        if (l < MEMN) {
            Ps[w][l] = ps0;
            Ps[w + 4][l] = ps1;
            if (w < 2) Ps[w + 8][l] = ps2;
        }
    }
    __syncthreads();

    // ---- Phase 5: state_f = state1 + 3*Hb + Psum . OHm ; emit bf16 ----
    {
        int d = t & 127;
        int qb = t >> 7;   // 0/1 -> q = qb + 2j
        float acc[5] = {0.f, 0.f, 0.f, 0.f, 0.f};
        for (int s = 0; s < MEMN; ++s) {
            int pp = (((d >> 3) ^ (s & 15)) << 3) | (d & 7);
            float ov = bf2f(OH_hi[s][pp]) + bf2f(OH_lo[s][pp]);
            #pragma unroll
            for (int j = 0; j < 5; ++j)
                acc[j] += Ps[qb + j * 2][s] * ov;
        }
        float hb3 = 3.f * stateM[NQ][d];
        #pragma unroll
        for (int j = 0; j < 5; ++j) {
            int q = qb + j * 2;
            stateb[((size_t)b * NQ + q) * EMBED + d] =
                __float2bfloat16(stateM[q][d] + hb3 + acc[j]);
        }
    }
}

// ---- Kernel 3 (R10-exact): MFMA GEMM out[160,32000] ----
__global__ __launch_bounds__(256) void k_out(const __hip_bfloat16* __restrict__ stateb,
                                             const float* __restrict__ outw,
                                             float* __restrict__ out) {
    __shared__ __align__(16) __hip_bfloat16 Alds[BN][EMBED + 8];
    __shared__ __align__(16) __hip_bfloat16 Blds[NV][EMBED + 8];
    int t = threadIdx.x;
    int vbase = blockIdx.x * NV;

    #pragma unroll
    for (int i = 0; i < 10; ++i) {
        int e = t + i * 256;
        int row = e >> 4, c8 = (e & 15) << 3;
        *(int4*)&Alds[row][c8] = *(const int4*)&stateb[row * EMBED + c8];
    }
    #pragma unroll
    for (int i = 0; i < 8; ++i) {
        int e = t + i * 256;
        int row = e >> 5, c4 = (e & 31) << 2;
        float4 w = *(const float4*)&outw[(size_t)(vbase + row) * EMBED + c4];
        short4 p;
        p.x = f2bf(w.x); p.y = f2bf(w.y); p.z = f2bf(w.z); p.w = f2bf(w.w);
        *(short4*)&Blds[row][c4] = p;
    }
    __syncthreads();

    int wv = t >> 6;
    int l = t & 63;
    int col16 = l & 15;
    int kg = l >> 4;

    v8s bfrag[4];
    #pragma unroll
    for (int k4 = 0; k4 < 4; ++k4)
        bfrag[k4] = *(v8s*)&Blds[(wv << 4) + col16][k4 * 32 + kg * 8];

    v4f acc[10];
    #pragma unroll
    for (int m = 0; m < 10; ++m) acc[m] = (v4f){0.f, 0.f, 0.f, 0.f};

    #pragma unroll
    for (int k4 = 0; k4 < 4; ++k4) {
        #pragma unroll
        for (int m = 0; m < 10; ++m) {
            v8s af = *(v8s*)&Alds[m * 16 + col16][k4 * 32 + kg * 8];
            acc[m] = MFMA16(af, bfrag[k4], acc[m], 0, 0, 0);
        }
    }

    int colg = vbase + (wv << 4) + col16;
    #pragma unroll
    for (int m = 0; m < 10; ++m) {
        #pragma unroll
        for (int i = 0; i < 4; ++i) {
            out[(size_t)(m * 16 + kg * 4 + i) * VOCAB + colg] = acc[m][i];
        }
    }
}

extern "C" void kernel_launch(void* const* d_in, const int* in_sizes, int n_in,
                              void* d_out, int out_size, void* d_ws, size_t ws_size,
                              hipStream_t stream) {
    const int*   ctx_query = (const int*)  d_in[0];
    const int*   story     = (const int*)  d_in[1];
    const float* A_w       = (const float*)d_in[2];
    const float* C_w       = (const float*)d_in[3];
    const float* B_w       = (const float*)d_in[4];
    const float* H_w       = (const float*)d_in[5];
    const float* H_b       = (const float*)d_in[6];
    const float* out_w     = (const float*)d_in[7];
    const float* TA        = (const float*)d_in[8];
    const float* TC        = (const float*)d_in[9];
    float* out = (float*)d_out;

    float* ws    = (float*)d_ws;
    float* state = ws;                                   // 160*128 f32
    float* memb  = state + BN * EMBED;                   // 800*128 f32
    float* outb  = memb + BATCH * MEMN * EMBED;          // 800*128 f32
    short* HwBhi = (short*)(outb + BATCH * MEMN * EMBED);// 128*128 bf16
    short* HwBlo = HwBhi + EMBED * EMBED;                // 128*128 bf16
    __hip_bfloat16* stateb = (__hip_bfloat16*)(HwBlo + EMBED * EMBED);  // 160*128 bf16

    k_embed<<<BN + BATCH * MEMN + EMBED, 128, 0, stream>>>(
        ctx_query, story, B_w, A_w, C_w, TA, TC, H_w, state, memb, outb, HwBhi, HwBlo);
    k_hops<<<BATCH, 256, 0, stream>>>(memb, outb, HwBhi, HwBlo, H_b, state, stateb);
    k_out<<<VOCAB / NV, 256, 0, stream>>>(stateb, out_w, out);
}